// Round 1
// 2218.986 us; speedup vs baseline: 1.1214x; 1.1214x over previous
//
#include <hip/hip_runtime.h>

// (B, L, C, H, O) = (4096, 256, 16, 128, 4)
#define NB 4096
#define NL 256
#define NC 16
#define NH 128
#define NO 4

typedef float f32x2 __attribute__((ext_vector_type(2)));

__device__ __forceinline__ float lane_bcast(float v, int l) {
  return __uint_as_float(__builtin_amdgcn_readlane(__float_as_uint(v), l));
}

__device__ __forceinline__ float fast_exp2(float x) {
#if __has_builtin(__builtin_amdgcn_exp2f)
  return __builtin_amdgcn_exp2f(x);
#else
  return exp2f(x);
#endif
}

__device__ __forceinline__ float fast_rcp(float x) {
#if __has_builtin(__builtin_amdgcn_rcpf)
  return __builtin_amdgcn_rcpf(x);
#else
  return 1.0f / x;
#endif
}

__device__ __forceinline__ f32x2 splat2(float x) {
  f32x2 r; r.x = x; r.y = x; return r;
}
__device__ __forceinline__ f32x2 fma2(f32x2 a, f32x2 b, f32x2 c) {
  return __builtin_elementwise_fma(a, b, c);
}

// Register-pin: opaque def the compiler cannot rematerialize or sink into the
// loop. Forces the loop-invariant weights to stay VGPR-resident (VGPR_Count=80
// in the previous build proves they were being reloaded per step).
#define PIN(x) asm volatile("" : "+v"(x))

// vf(z, xdot):  h = relu(z@W1+b1); g = tanh(h@W2+b2); k = g . xdot
// Weights pre-scaled by 2*log2(e) so tanh(x) = 1 - 2/(exp2(sx)+1).
// All (hA,hB) pair math packed as f32x2 -> v_pk_{fma,mul,add}_f32.
// Bit-identical op tree to the scalar version (pk = two independent fmas).
#define VF(ZS, XDV, SXV, KOUT)                                                \
  {                                                                           \
    f32x2 zs_ = (ZS);                                                         \
    f32x2 p_ = fma2(splat2(zs_.x), w1a_, splat2(zs_.y) * w1b_);               \
    _Pragma("unroll") for (int m_ = 32; m_ >= 1; m_ >>= 1) {                  \
      p_.x += __shfl_xor(p_.x, m_, 64);                                       \
      p_.y += __shfl_xor(p_.y, m_, 64);                                       \
    }                                                                         \
    float hh0 = fmaxf(p_.x + b1_0, 0.0f);                                     \
    float hh1 = fmaxf(p_.y + b1_1, 0.0f);                                     \
    f32x2 h0v_ = splat2(hh0), h1v_ = splat2(hh1);                             \
    f32x2 acc_ = {0.0f, 0.0f};                                                \
    _Pragma("unroll") for (int c_ = 0; c_ < NC; ++c_) {                       \
      f32x2 xcv_ = splat2(lane_bcast((XDV), c_));                             \
      f32x2 s_ = fma2(w2a[c_], h0v_, fma2(w2b[c_], h1v_, b2v[c_]));           \
      f32x2 e_;                                                               \
      e_.x = fast_exp2(s_.x);                                                 \
      e_.y = fast_exp2(s_.y);                                                 \
      f32x2 d_ = e_ + 1.0f;                                                   \
      f32x2 inv_;                                                             \
      inv_.x = fast_rcp(d_.x);                                                \
      inv_.y = fast_rcp(d_.y);                                                \
      acc_ = fma2(xcv_, inv_, acc_);                                          \
    }                                                                         \
    (KOUT) = fma2(splat2(-2.0f), acc_, splat2(SXV));                          \
  }

#define STORE_OUT(T, ZS)                                                      \
  {                                                                           \
    f32x2 zz_ = (ZS);                                                         \
    f32x2 q01 = fma2(splat2(zz_.x), woa01, splat2(zz_.y) * wob01);            \
    f32x2 q23 = fma2(splat2(zz_.x), woa23, splat2(zz_.y) * wob23);            \
    _Pragma("unroll") for (int m_ = 32; m_ >= 1; m_ >>= 1) {                  \
      q01.x += __shfl_xor(q01.x, m_, 64);                                     \
      q01.y += __shfl_xor(q01.y, m_, 64);                                     \
      q23.x += __shfl_xor(q23.x, m_, 64);                                     \
      q23.y += __shfl_xor(q23.y, m_, 64);                                     \
    }                                                                         \
    if (lane == 0) {                                                          \
      float4 r_;                                                              \
      r_.x = q01.x + bo0;                                                     \
      r_.y = q01.y + bo1;                                                     \
      r_.z = q23.x + bo2;                                                     \
      r_.w = q23.y + bo3;                                                     \
      *(float4*)(obase + (size_t)(T)*NO) = r_;                                \
    }                                                                         \
  }

__global__ __launch_bounds__(256, 2) void ncde_kernel(
    const float* __restrict__ coeffs,  // (B, L-1, 4*C)
    const float* __restrict__ W_init,  // (C, H)
    const float* __restrict__ b_init,  // (H,)
    const float* __restrict__ W1,      // (H, 2)
    const float* __restrict__ b1,      // (2,)
    const float* __restrict__ W2,      // (2, H*C)
    const float* __restrict__ b2,      // (H*C,)
    const float* __restrict__ W_out,   // (H, O)
    const float* __restrict__ b_out,   // (O,)
    float* __restrict__ out)           // (B, L, O)
{
  const int lane = threadIdx.x & 63;
  const int wid  = threadIdx.x >> 6;
  const int bat  = blockIdx.x * 4 + wid;  // one wave per batch element
  const int hA = lane;
  const int hB = lane + 64;
  const float SC = 2.885390081777927f;  // 2*log2(e)

  // ---- loop-invariant weights, packed (hA,hB) pairs ----
  f32x2 w2a[NC], w2b[NC], b2v[NC];
#pragma unroll
  for (int c = 0; c < NC; ++c) {
    w2a[c].x = W2[hA * NC + c] * SC;
    w2a[c].y = W2[hB * NC + c] * SC;
    w2b[c].x = W2[NH * NC + hA * NC + c] * SC;
    w2b[c].y = W2[NH * NC + hB * NC + c] * SC;
    b2v[c].x = b2[hA * NC + c] * SC;
    b2v[c].y = b2[hB * NC + c] * SC;
  }
  f32x2 w1a_, w1b_, woa01, wob01, woa23, wob23;
  w1a_.x = W1[hA * 2 + 0]; w1a_.y = W1[hA * 2 + 1];
  w1b_.x = W1[hB * 2 + 0]; w1b_.y = W1[hB * 2 + 1];
  woa01.x = W_out[hA * NO + 0]; woa01.y = W_out[hA * NO + 1];
  woa23.x = W_out[hA * NO + 2]; woa23.y = W_out[hA * NO + 3];
  wob01.x = W_out[hB * NO + 0]; wob01.y = W_out[hB * NO + 1];
  wob23.x = W_out[hB * NO + 2]; wob23.y = W_out[hB * NO + 3];
  const float bo0 = b_out[0], bo1 = b_out[1], bo2 = b_out[2], bo3 = b_out[3];
  const float b1_0 = b1[0], b1_1 = b1[1];

  // Force all loop-invariant weights VGPR-resident for the whole kernel.
#pragma unroll
  for (int c = 0; c < NC; ++c) { PIN(w2a[c]); PIN(w2b[c]); PIN(b2v[c]); }
  PIN(w1a_); PIN(w1b_);
  PIN(woa01); PIN(wob01); PIN(woa23); PIN(wob23);

  const float* crow = coeffs + (size_t)bat * (NL - 1) * (4 * NC);
  float* obase = out + (size_t)bat * NL * NO;

  // ---- z0 = X0 @ W_init + b_init ----
  float v0 = crow[lane];
  f32x2 z;
  z.x = b_init[hA];
  z.y = b_init[hB];
#pragma unroll
  for (int c = 0; c < NC; ++c) {
    f32x2 wi;
    wi.x = W_init[c * NH + hA];
    wi.y = W_init[c * NH + hB];
    z = fma2(splat2(lane_bcast(v0, c)), wi, z);
  }

  STORE_OUT(0, z);

  const int cl = lane & 15;
#pragma unroll 1
  for (int s = 0; s < NL - 1; ++s) {
    float vrow = crow[s * 64 + lane];
    float vb = __shfl(vrow, 16 + cl, 64);
    float vcm = __shfl(vrow, 32 + cl, 64);
    float vd = __shfl(vrow, 48 + cl, 64);
    float xd0 = vb;
    float xdh = fmaf(0.25f, vd, fmaf(0.5f, vcm, vb));
    float xd1 = vb + (vcm + vd);

    // per-xdot component sums over the 16-group (wave-uniform result)
    float sx0 = xd0, sxh = xdh, sx1 = xd1;
#pragma unroll
    for (int m = 8; m >= 1; m >>= 1) {
      sx0 += __shfl_xor(sx0, m, 64);
      sxh += __shfl_xor(sxh, m, 64);
      sx1 += __shfl_xor(sx1, m, 64);
    }

    f32x2 k1, k2, k3, k4;
    VF(z, xd0, sx0, k1);
    VF(fma2(splat2(0.5f), k1, z), xdh, sxh, k2);
    VF(fma2(splat2(0.5f), k2, z), xdh, sxh, k3);
    VF(z + k3, xd1, sx1, k4);

    z = z + (k1 + 2.0f * (k2 + k3) + k4) * (1.0f / 6.0f);

    STORE_OUT(s + 1, z);
  }
}

extern "C" void kernel_launch(void* const* d_in, const int* in_sizes, int n_in,
                              void* d_out, int out_size, void* d_ws, size_t ws_size,
                              hipStream_t stream) {
  const float* coeffs = (const float*)d_in[0];
  const float* W_init = (const float*)d_in[1];
  const float* b_init = (const float*)d_in[2];
  const float* W1     = (const float*)d_in[3];
  const float* b1     = (const float*)d_in[4];
  const float* W2     = (const float*)d_in[5];
  const float* b2     = (const float*)d_in[6];
  const float* W_out  = (const float*)d_in[7];
  const float* b_out  = (const float*)d_in[8];
  float* out = (float*)d_out;

  ncde_kernel<<<NB / 4, 256, 0, stream>>>(coeffs, W_init, b_init, W1, b1, W2,
                                          b2, W_out, b_out, out);
}